// Round 8
// baseline (75.484 us; speedup 1.0000x reference)
//
#include <hip/hip_runtime.h>

// Problem constants (match reference)
constexpr int Bn = 32;      // batch
constexpr int Nn = 512;     // logical qubits
constexpr int Qq = 512;     // physical qubits
constexpr int Ee = 4096;    // edges per batch
constexpr int Mtot = Bn * Nn;  // 16384 rows of P_flat
constexpr int CAP = 512;    // edge-bin capacity (expected max ~300)

typedef short bf16x8 __attribute__((ext_vector_type(8)));
typedef float f32x4 __attribute__((ext_vector_type(4)));
typedef unsigned short u16;
typedef unsigned short u16x8 __attribute__((ext_vector_type(8)));
typedef unsigned int u32;

__device__ inline u16 f2bf(float f) {   // RNE float->bf16
    union { float f; unsigned u; } x; x.f = f;
    unsigned r = x.u + 0x7FFFu + ((x.u >> 16) & 1u);
    return (u16)(r >> 16);
}
__device__ inline void gload_lds16(const u16* g, u16* l) {
    __builtin_amdgcn_global_load_lds(
        (const __attribute__((address_space(1))) unsigned int*)g,
        (__attribute__((address_space(3))) unsigned int*)l, 16, 0, 0);
}

// tile-index-in-batch from (mt,nt); lower-triangle cover mt>=2*nt, 20 tiles
__device__ inline int tile_tt(int mt, int nt) {
    return mt + (nt == 0 ? 0 : nt == 1 ? 6 : nt == 2 ? 10 : 12);
}

// ---------------------------------------------------------------------------
// Kernel 1 (merged):
//   blocks   0..31  -> inv_w[b] (+ out[0]=0 on block 0)
//   blocks  32..287 -> Dbf = bf16(3*max(d_hw-1,0))
//   blocks 288..415 -> bin edges by S-tile: bins[bin][pos] = (hi<<9|lo, w)
//   (bincount zeroed by a hipMemsetAsync before this kernel)
// ---------------------------------------------------------------------------
__global__ __launch_bounds__(256) void k_init(const float* __restrict__ edge_w,
                                              const float* __restrict__ d_hw,
                                              const int* __restrict__ esrc,
                                              const int* __restrict__ edst,
                                              float* __restrict__ inv_w,
                                              u16* __restrict__ Dbf,
                                              u32* __restrict__ bincount,
                                              uint2* __restrict__ bins,
                                              float* __restrict__ out) {
    if (blockIdx.x < 32) {
        int b = blockIdx.x;
        const float* w = edge_w + (size_t)b * Ee;
        float s = 0.f;
        for (int i = threadIdx.x; i < Ee; i += 256) s += w[i];
        for (int off = 32; off; off >>= 1) s += __shfl_down(s, off);
        __shared__ float red[4];
        int wave = threadIdx.x >> 6, lane = threadIdx.x & 63;
        if (lane == 0) red[wave] = s;
        __syncthreads();
        if (threadIdx.x == 0) {
            float t = red[0] + red[1] + red[2] + red[3];
            inv_w[b] = 1.0f / fmaxf(t, 1e-8f);
            if (b == 0) out[0] = 0.f;
        }
    } else if (blockIdx.x < 288) {
        int i = (blockIdx.x - 32) * 256 + threadIdx.x;   // 4 elems per thread
        float4 v = ((const float4*)d_hw)[i];
        ushort4 o;
        o.x = f2bf(3.f * fmaxf(v.x - 1.f, 0.f));
        o.y = f2bf(3.f * fmaxf(v.y - 1.f, 0.f));
        o.z = f2bf(3.f * fmaxf(v.z - 1.f, 0.f));
        o.w = f2bf(3.f * fmaxf(v.w - 1.f, 0.f));
        ((ushort4*)Dbf)[i] = o;
    } else {
        // edge binning: 128 blocks x 1024 edges
        int base = (blockIdx.x - 288) * 1024;
        for (int i = threadIdx.x; i < 1024; i += 256) {
            int idx = base + i;
            int b = idx >> 12;
            int s = esrc[idx];
            int d = edst[idx];
            float w = edge_w[idx];
            int hi = max(s, d), lo = min(s, d);
            int bin = b * 20 + tile_tt(hi >> 6, lo >> 7);
            u32 pos = atomicAdd(&bincount[bin], 1u);
            if (pos < CAP) {
                bins[(size_t)bin * CAP + pos] =
                    make_uint2(((u32)hi << 9) | (u32)lo, __float_as_uint(w));
            }
        }
    }
}

// ---------------------------------------------------------------------------
// Kernel 2: fused cast+GEMM1:  G = bf16(P) * D^T  (D symmetric).
//   BM=64, BN=128, BK=32, 4 waves in 2x2, acc[2][4]/wave.
//   A reg-staged from f32 P (f2bf -> ds_write_b128, linear LDS); B via
//   global_load_lds width-16. N0==0 blocks publish bf16 A-tiles to Pbf.
//   1D grid 1024 + bijective XCD-chunk swizzle.
// ---------------------------------------------------------------------------
__global__ __launch_bounds__(256) void k_gemm1(const float* __restrict__ P,
                                               const u16* __restrict__ Dbf,
                                               u16* __restrict__ Pbf,
                                               u16* __restrict__ G) {
    __shared__ u16 As[64 * 32];    // 4 KB
    __shared__ u16 Bs[128 * 32];   // 8 KB
    const int tid = threadIdx.x;
    const int lane = tid & 63;
    const int wave = tid >> 6;
    const int wm = wave >> 1, wn = wave & 1;

    int t = (blockIdx.x & 7) * 128 + (blockIdx.x >> 3);
    int xt = t & 3, yt = t >> 2;        // consecutive t share yt (A-panel)
    const int M0 = yt * 64, N0 = xt * 128;

    const int srow = tid >> 2;            // 0..63
    const int scol = (tid & 3) * 8;

    const float* gA = P + (size_t)(M0 + srow) * Qq + scol;
    const u16* gB = Dbf + (size_t)(N0 + srow) * Qq + scol;
    u16* pOut = Pbf + (size_t)(M0 + srow) * Qq + scol;

    u16* lA = As + srow * 32 + scol;      // linear, = tid*16 bytes
    u16* lB0 = Bs + wave * 512;           // rows 0..63
    u16* lB1 = Bs + 2048 + wave * 512;    // rows 64..127

    f32x4 acc[2][4] = {};

    for (int k0 = 0; k0 < Qq; k0 += 32) {
        gload_lds16(gB + k0, lB0);
        gload_lds16(gB + (size_t)64 * Qq + k0, lB1);
        float4 v0 = *(const float4*)(gA + k0);
        float4 v1 = *(const float4*)(gA + k0 + 4);
        u16x8 o;
        o[0] = f2bf(v0.x); o[1] = f2bf(v0.y); o[2] = f2bf(v0.z); o[3] = f2bf(v0.w);
        o[4] = f2bf(v1.x); o[5] = f2bf(v1.y); o[6] = f2bf(v1.z); o[7] = f2bf(v1.w);
        *(u16x8*)lA = o;
        if (N0 == 0) *(u16x8*)(pOut + k0) = o;   // publish bf16 P for GEMM2
        __syncthreads();

        bf16x8 a[2], b[4];
        #pragma unroll
        for (int mi = 0; mi < 2; ++mi)
            a[mi] = *(const bf16x8*)&As[(wm * 32 + mi * 16 + (lane & 15)) * 32 + (lane >> 4) * 8];
        #pragma unroll
        for (int ni = 0; ni < 4; ++ni)
            b[ni] = *(const bf16x8*)&Bs[(wn * 64 + ni * 16 + (lane & 15)) * 32 + (lane >> 4) * 8];
        #pragma unroll
        for (int mi = 0; mi < 2; ++mi)
            #pragma unroll
            for (int ni = 0; ni < 4; ++ni)
                acc[mi][ni] = __builtin_amdgcn_mfma_f32_16x16x32_bf16(a[mi], b[ni], acc[mi][ni], 0, 0, 0);
        __syncthreads();
    }

    const int r0 = (lane >> 4) * 4;
    const int c = lane & 15;
    #pragma unroll
    for (int mi = 0; mi < 2; ++mi) {
        #pragma unroll
        for (int ni = 0; ni < 4; ++ni) {
            int row = M0 + wm * 32 + mi * 16 + r0;
            int col = N0 + wn * 64 + ni * 16 + c;
            #pragma unroll
            for (int r = 0; r < 4; ++r)
                G[(size_t)(row + r) * Qq + col] = f2bf(acc[mi][ni][r]);
        }
    }
}

// ---------------------------------------------------------------------------
// Kernel 3: GEMM2 + fused edge reduction.  S_b = G_b * P_b^T tile (64x128)
//   stays in LDS (f32, +1-pad); the block then reduces ITS binned edges:
//   out += sum w_e * Stile[hi&63][lo&127] * inv_w[b] / B. No S in global.
//   640 blocks (lower-triangle cover), XCD-chunk swizzle.
// ---------------------------------------------------------------------------
__global__ __launch_bounds__(256) void k_gemm2(const u16* __restrict__ A,
                                               const u16* __restrict__ Bt,
                                               const u32* __restrict__ bincount,
                                               const uint2* __restrict__ bins,
                                               const float* __restrict__ inv_w,
                                               float* __restrict__ out) {
    __shared__ char smem[64 * 129 * 4];            // 33024 B, aliased:
    u16* As = (u16*)smem;                          //  4 KB staging A
    u16* Bs = (u16*)(smem + 4096);                 //  8 KB staging B
    float* Stile = (float*)smem;                   //  64x129 f32 tile
    __shared__ float red[4];

    const int tid = threadIdx.x;
    const int lane = tid & 63;
    const int wave = tid >> 6;
    const int wm = wave >> 1, wn = wave & 1;

    int t = (blockIdx.x & 7) * 80 + (blockIdx.x >> 3);   // nwg=640=8*80
    int bb = t / 20, tt = t % 20;
    int nt = (tt < 8) ? 0 : (tt < 14) ? 1 : (tt < 18) ? 2 : 3;
    int mt = (tt < 8) ? tt : (tt < 14) ? tt - 6 : (tt < 18) ? tt - 10 : tt - 12;
    const int M0 = bb * 512 + mt * 64, N0 = nt * 128;
    const u16* Bbase = Bt + (size_t)bb * Nn * Qq;

    const int srow = tid >> 2;
    const int scol = (tid & 3) * 8;

    const u16* gA = A + (size_t)(M0 + srow) * Qq + scol;
    const u16* gB = Bbase + (size_t)(N0 + srow) * Qq + scol;

    u16* lA0 = As + wave * 512;
    u16* lB0 = Bs + wave * 512;
    u16* lB1 = Bs + 2048 + wave * 512;

    f32x4 acc[2][4] = {};

    for (int k0 = 0; k0 < Qq; k0 += 32) {
        gload_lds16(gA + k0, lA0);
        gload_lds16(gB + k0, lB0);
        gload_lds16(gB + (size_t)64 * Qq + k0, lB1);
        __syncthreads();

        bf16x8 a[2], b[4];
        #pragma unroll
        for (int mi = 0; mi < 2; ++mi)
            a[mi] = *(const bf16x8*)&As[(wm * 32 + mi * 16 + (lane & 15)) * 32 + (lane >> 4) * 8];
        #pragma unroll
        for (int ni = 0; ni < 4; ++ni)
            b[ni] = *(const bf16x8*)&Bs[(wn * 64 + ni * 16 + (lane & 15)) * 32 + (lane >> 4) * 8];
        #pragma unroll
        for (int mi = 0; mi < 2; ++mi)
            #pragma unroll
            for (int ni = 0; ni < 4; ++ni)
                acc[mi][ni] = __builtin_amdgcn_mfma_f32_16x16x32_bf16(a[mi], b[ni], acc[mi][ni], 0, 0, 0);
        __syncthreads();
    }

    // park S-tile in LDS (f32; rows padded to 129 to break 4-way bank conflict)
    const int r0 = (lane >> 4) * 4;
    const int c = lane & 15;
    #pragma unroll
    for (int mi = 0; mi < 2; ++mi)
        #pragma unroll
        for (int ni = 0; ni < 4; ++ni)
            #pragma unroll
            for (int r = 0; r < 4; ++r)
                Stile[(wm * 32 + mi * 16 + r0 + r) * 129 + wn * 64 + ni * 16 + c] =
                    acc[mi][ni][r];
    __syncthreads();

    // reduce this tile's edges
    int bin = bb * 20 + tt;
    int cnt = min((int)bincount[bin], CAP);
    const uint2* list = bins + (size_t)bin * CAP;
    float local = 0.f;
    for (int i = tid; i < cnt; i += 256) {
        uint2 e = list[i];
        int hi = (e.x >> 9) & 511, lo = e.x & 511;
        float w = __uint_as_float(e.y);
        local += w * Stile[(hi & 63) * 129 + (lo & 127)];
    }
    for (int off = 32; off; off >>= 1) local += __shfl_down(local, off);
    if (lane == 0) red[wave] = local;
    __syncthreads();
    if (tid == 0)
        atomicAdd(out, (red[0] + red[1] + red[2] + red[3]) * inv_w[bb] * (1.0f / Bn));
}

// ---------------------------------------------------------------------------
extern "C" void kernel_launch(void* const* d_in, const int* in_sizes, int n_in,
                              void* d_out, int out_size, void* d_ws, size_t ws_size,
                              hipStream_t stream) {
    const float* P    = (const float*)d_in[0];   // [B,N,Q] f32
    const float* d_hw = (const float*)d_in[1];   // [Q,Q]   f32
    const int* esrc   = (const int*)d_in[2];     // [B,E]
    const int* edst   = (const int*)d_in[3];     // [B,E]
    const float* ew   = (const float*)d_in[4];   // [B,E]
    float* out = (float*)d_out;

    char* ws = (char*)d_ws;
    float* inv_w = (float*)ws;                           // 32 f32
    u32* bincount = (u32*)(ws + 1024);                   // 640 u32 (2.5 KB)
    uint2* bins = (uint2*)(ws + 8192);                   // 640*512*8 = 2.62 MB
    u16* Pbf = (u16*)(ws + 8192 + (size_t)640 * CAP * 8);       // 16.78 MB
    u16* Dbf = Pbf + (size_t)Mtot * Qq;                         //  0.52 MB
    u16* G   = Dbf + (size_t)Qq * Qq;                           // 16.78 MB

    hipMemsetAsync(bincount, 0, 640 * sizeof(u32), stream);
    k_init<<<dim3(416), dim3(256), 0, stream>>>(
        ew, d_hw, esrc, edst, inv_w, Dbf, bincount, bins, out);
    k_gemm1<<<dim3(1024), dim3(256), 0, stream>>>(P, Dbf, Pbf, G);
    k_gemm2<<<dim3(640), dim3(256), 0, stream>>>(G, Pbf, bincount, bins, inv_w, out);
}

// Round 9
// 54.476 us; speedup vs baseline: 1.3856x; 1.3856x over previous
//
#include <hip/hip_runtime.h>

// Problem constants (match reference)
constexpr int Bn = 32;      // batch
constexpr int Nn = 512;     // logical qubits
constexpr int Qq = 512;     // physical qubits
constexpr int Ee = 4096;    // edges per batch
constexpr int Mtot = Bn * Nn;  // 16384 rows of P_flat
constexpr int CAP = 512;    // edge-bin capacity (expected max ~340)

typedef short bf16x8 __attribute__((ext_vector_type(8)));
typedef float f32x4 __attribute__((ext_vector_type(4)));
typedef unsigned short u16;
typedef unsigned short u16x8 __attribute__((ext_vector_type(8)));
typedef unsigned int u32;

__device__ inline u16 f2bf(float f) {   // RNE float->bf16
    union { float f; unsigned u; } x; x.f = f;
    unsigned r = x.u + 0x7FFFu + ((x.u >> 16) & 1u);
    return (u16)(r >> 16);
}
__device__ inline void gload_lds16(const u16* g, u16* l) {
    __builtin_amdgcn_global_load_lds(
        (const __attribute__((address_space(1))) unsigned int*)g,
        (__attribute__((address_space(3))) unsigned int*)l, 16, 0, 0);
}

// tile-index-in-batch from (mt,nt); lower-triangle cover mt>=2*nt, 20 tiles
__device__ inline int tile_tt(int mt, int nt) {
    return mt + (nt == 0 ? 0 : nt == 1 ? 6 : nt == 2 ? 10 : 12);
}

// ---------------------------------------------------------------------------
// Kernel 1 (merged, NO global memset needed):
//   blocks   0..31  -> inv_w[b] (+ out[0]=0 on block 0)
//   blocks  32..287 -> Dbf = bf16(3*max(d_hw-1,0))
//   blocks 288..319 -> bin batch b's edges by S-tile (LDS counters; block
//                      owns its 20 bins exclusively -> writes bincount
//                      unconditionally, no pre-zero, no global atomics)
// ---------------------------------------------------------------------------
__global__ __launch_bounds__(256) void k_init(const float* __restrict__ edge_w,
                                              const float* __restrict__ d_hw,
                                              const int* __restrict__ esrc,
                                              const int* __restrict__ edst,
                                              float* __restrict__ inv_w,
                                              u16* __restrict__ Dbf,
                                              u32* __restrict__ bincount,
                                              uint2* __restrict__ bins,
                                              float* __restrict__ out) {
    __shared__ float red[4];
    __shared__ u32 cnt[20];
    if (blockIdx.x < 32) {
        int b = blockIdx.x;
        const float* w = edge_w + (size_t)b * Ee;
        float s = 0.f;
        for (int i = threadIdx.x; i < Ee; i += 256) s += w[i];
        for (int off = 32; off; off >>= 1) s += __shfl_down(s, off);
        int wave = threadIdx.x >> 6, lane = threadIdx.x & 63;
        if (lane == 0) red[wave] = s;
        __syncthreads();
        if (threadIdx.x == 0) {
            float t = red[0] + red[1] + red[2] + red[3];
            inv_w[b] = 1.0f / fmaxf(t, 1e-8f);
            if (b == 0) out[0] = 0.f;
        }
    } else if (blockIdx.x < 288) {
        int i = (blockIdx.x - 32) * 256 + threadIdx.x;   // 4 elems per thread
        float4 v = ((const float4*)d_hw)[i];
        ushort4 o;
        o.x = f2bf(3.f * fmaxf(v.x - 1.f, 0.f));
        o.y = f2bf(3.f * fmaxf(v.y - 1.f, 0.f));
        o.z = f2bf(3.f * fmaxf(v.z - 1.f, 0.f));
        o.w = f2bf(3.f * fmaxf(v.w - 1.f, 0.f));
        ((ushort4*)Dbf)[i] = o;
    } else {
        int b = blockIdx.x - 288;            // one block per batch
        if (threadIdx.x < 20) cnt[threadIdx.x] = 0;
        __syncthreads();
        int base = b * Ee;
        for (int i = threadIdx.x; i < Ee; i += 256) {
            int idx = base + i;
            int s = esrc[idx];
            int d = edst[idx];
            float w = edge_w[idx];
            int hi = max(s, d), lo = min(s, d);
            int tt = tile_tt(hi >> 6, lo >> 7);
            u32 pos = atomicAdd(&cnt[tt], 1u);   // LDS atomic
            if (pos < CAP)
                bins[(size_t)(b * 20 + tt) * CAP + pos] =
                    make_uint2(((u32)hi << 9) | (u32)lo, __float_as_uint(w));
        }
        __syncthreads();
        if (threadIdx.x < 20) bincount[b * 20 + threadIdx.x] = cnt[threadIdx.x];
    }
}

// ---------------------------------------------------------------------------
// Kernel 2: fused cast+GEMM1:  G = bf16(P) * D^T  (D symmetric).
//   BM=64, BN=128, BK=32, 4 waves in 2x2, acc[2][4]/wave.
//   A reg-staged from f32 P (f2bf -> ds_write_b128, linear LDS); B via
//   global_load_lds width-16. N0==0 blocks publish bf16 A-tiles to Pbf.
//   1D grid 1024 + bijective XCD-chunk swizzle.
// ---------------------------------------------------------------------------
__global__ __launch_bounds__(256) void k_gemm1(const float* __restrict__ P,
                                               const u16* __restrict__ Dbf,
                                               u16* __restrict__ Pbf,
                                               u16* __restrict__ G) {
    __shared__ u16 As[64 * 32];    // 4 KB
    __shared__ u16 Bs[128 * 32];   // 8 KB
    const int tid = threadIdx.x;
    const int lane = tid & 63;
    const int wave = tid >> 6;
    const int wm = wave >> 1, wn = wave & 1;

    int t = (blockIdx.x & 7) * 128 + (blockIdx.x >> 3);
    int xt = t & 3, yt = t >> 2;        // consecutive t share yt (A-panel)
    const int M0 = yt * 64, N0 = xt * 128;

    const int srow = tid >> 2;            // 0..63
    const int scol = (tid & 3) * 8;

    const float* gA = P + (size_t)(M0 + srow) * Qq + scol;
    const u16* gB = Dbf + (size_t)(N0 + srow) * Qq + scol;
    u16* pOut = Pbf + (size_t)(M0 + srow) * Qq + scol;

    u16* lA = As + srow * 32 + scol;      // linear, = tid*16 bytes
    u16* lB0 = Bs + wave * 512;           // rows 0..63
    u16* lB1 = Bs + 2048 + wave * 512;    // rows 64..127

    f32x4 acc[2][4] = {};

    for (int k0 = 0; k0 < Qq; k0 += 32) {
        gload_lds16(gB + k0, lB0);
        gload_lds16(gB + (size_t)64 * Qq + k0, lB1);
        float4 v0 = *(const float4*)(gA + k0);
        float4 v1 = *(const float4*)(gA + k0 + 4);
        u16x8 o;
        o[0] = f2bf(v0.x); o[1] = f2bf(v0.y); o[2] = f2bf(v0.z); o[3] = f2bf(v0.w);
        o[4] = f2bf(v1.x); o[5] = f2bf(v1.y); o[6] = f2bf(v1.z); o[7] = f2bf(v1.w);
        *(u16x8*)lA = o;
        if (N0 == 0) *(u16x8*)(pOut + k0) = o;   // publish bf16 P for GEMM2
        __syncthreads();

        bf16x8 a[2], b[4];
        #pragma unroll
        for (int mi = 0; mi < 2; ++mi)
            a[mi] = *(const bf16x8*)&As[(wm * 32 + mi * 16 + (lane & 15)) * 32 + (lane >> 4) * 8];
        #pragma unroll
        for (int ni = 0; ni < 4; ++ni)
            b[ni] = *(const bf16x8*)&Bs[(wn * 64 + ni * 16 + (lane & 15)) * 32 + (lane >> 4) * 8];
        #pragma unroll
        for (int mi = 0; mi < 2; ++mi)
            #pragma unroll
            for (int ni = 0; ni < 4; ++ni)
                acc[mi][ni] = __builtin_amdgcn_mfma_f32_16x16x32_bf16(a[mi], b[ni], acc[mi][ni], 0, 0, 0);
        __syncthreads();
    }

    const int r0 = (lane >> 4) * 4;
    const int c = lane & 15;
    #pragma unroll
    for (int mi = 0; mi < 2; ++mi) {
        #pragma unroll
        for (int ni = 0; ni < 4; ++ni) {
            int row = M0 + wm * 32 + mi * 16 + r0;
            int col = N0 + wn * 64 + ni * 16 + c;
            #pragma unroll
            for (int r = 0; r < 4; ++r)
                G[(size_t)(row + r) * Qq + col] = f2bf(acc[mi][ni][r]);
        }
    }
}

// ---------------------------------------------------------------------------
// Kernel 3: GEMM2 + fused edge reduction.  S_b = G_b * P_b^T tile (64x128)
//   stays in LDS (f32, +1-pad); the block then reduces ITS binned edges:
//   out += sum w_e * Stile[hi&63][lo&127] * inv_w[b] / B. No S in global.
//   640 blocks (lower-triangle cover), XCD-chunk swizzle.
// ---------------------------------------------------------------------------
__global__ __launch_bounds__(256) void k_gemm2(const u16* __restrict__ A,
                                               const u16* __restrict__ Bt,
                                               const u32* __restrict__ bincount,
                                               const uint2* __restrict__ bins,
                                               const float* __restrict__ inv_w,
                                               float* __restrict__ out) {
    __shared__ char smem[64 * 129 * 4];            // 33024 B, aliased:
    u16* As = (u16*)smem;                          //  4 KB staging A
    u16* Bs = (u16*)(smem + 4096);                 //  8 KB staging B
    float* Stile = (float*)smem;                   //  64x129 f32 tile
    __shared__ float red[4];

    const int tid = threadIdx.x;
    const int lane = tid & 63;
    const int wave = tid >> 6;
    const int wm = wave >> 1, wn = wave & 1;

    int t = (blockIdx.x & 7) * 80 + (blockIdx.x >> 3);   // nwg=640=8*80
    int bb = t / 20, tt = t % 20;
    int nt = (tt < 8) ? 0 : (tt < 14) ? 1 : (tt < 18) ? 2 : 3;
    int mt = (tt < 8) ? tt : (tt < 14) ? tt - 6 : (tt < 18) ? tt - 10 : tt - 12;
    const int M0 = bb * 512 + mt * 64, N0 = nt * 128;
    const u16* Bbase = Bt + (size_t)bb * Nn * Qq;

    const int srow = tid >> 2;
    const int scol = (tid & 3) * 8;

    const u16* gA = A + (size_t)(M0 + srow) * Qq + scol;
    const u16* gB = Bbase + (size_t)(N0 + srow) * Qq + scol;

    u16* lA0 = As + wave * 512;
    u16* lB0 = Bs + wave * 512;
    u16* lB1 = Bs + 2048 + wave * 512;

    f32x4 acc[2][4] = {};

    for (int k0 = 0; k0 < Qq; k0 += 32) {
        gload_lds16(gA + k0, lA0);
        gload_lds16(gB + k0, lB0);
        gload_lds16(gB + (size_t)64 * Qq + k0, lB1);
        __syncthreads();

        bf16x8 a[2], b[4];
        #pragma unroll
        for (int mi = 0; mi < 2; ++mi)
            a[mi] = *(const bf16x8*)&As[(wm * 32 + mi * 16 + (lane & 15)) * 32 + (lane >> 4) * 8];
        #pragma unroll
        for (int ni = 0; ni < 4; ++ni)
            b[ni] = *(const bf16x8*)&Bs[(wn * 64 + ni * 16 + (lane & 15)) * 32 + (lane >> 4) * 8];
        #pragma unroll
        for (int mi = 0; mi < 2; ++mi)
            #pragma unroll
            for (int ni = 0; ni < 4; ++ni)
                acc[mi][ni] = __builtin_amdgcn_mfma_f32_16x16x32_bf16(a[mi], b[ni], acc[mi][ni], 0, 0, 0);
        __syncthreads();
    }

    // park S-tile in LDS (f32; rows padded to 129 to break 4-way bank conflict)
    const int r0 = (lane >> 4) * 4;
    const int c = lane & 15;
    #pragma unroll
    for (int mi = 0; mi < 2; ++mi)
        #pragma unroll
        for (int ni = 0; ni < 4; ++ni)
            #pragma unroll
            for (int r = 0; r < 4; ++r)
                Stile[(wm * 32 + mi * 16 + r0 + r) * 129 + wn * 64 + ni * 16 + c] =
                    acc[mi][ni][r];
    __syncthreads();

    // reduce this tile's edges
    int bin = bb * 20 + tt;
    int cnt = min((int)bincount[bin], CAP);
    const uint2* list = bins + (size_t)bin * CAP;
    float local = 0.f;
    for (int i = tid; i < cnt; i += 256) {
        uint2 e = list[i];
        int hi = (e.x >> 9) & 511, lo = e.x & 511;
        float w = __uint_as_float(e.y);
        local += w * Stile[(hi & 63) * 129 + (lo & 127)];
    }
    for (int off = 32; off; off >>= 1) local += __shfl_down(local, off);
    if (lane == 0) red[wave] = local;
    __syncthreads();
    if (tid == 0)
        atomicAdd(out, (red[0] + red[1] + red[2] + red[3]) * inv_w[bb] * (1.0f / Bn));
}

// ---------------------------------------------------------------------------
extern "C" void kernel_launch(void* const* d_in, const int* in_sizes, int n_in,
                              void* d_out, int out_size, void* d_ws, size_t ws_size,
                              hipStream_t stream) {
    const float* P    = (const float*)d_in[0];   // [B,N,Q] f32
    const float* d_hw = (const float*)d_in[1];   // [Q,Q]   f32
    const int* esrc   = (const int*)d_in[2];     // [B,E]
    const int* edst   = (const int*)d_in[3];     // [B,E]
    const float* ew   = (const float*)d_in[4];   // [B,E]
    float* out = (float*)d_out;

    char* ws = (char*)d_ws;
    float* inv_w = (float*)ws;                           // 32 f32
    u32* bincount = (u32*)(ws + 1024);                   // 640 u32 (2.5 KB)
    uint2* bins = (uint2*)(ws + 8192);                   // 640*512*8 = 2.62 MB
    u16* Pbf = (u16*)(ws + 8192 + (size_t)640 * CAP * 8);       // 16.78 MB
    u16* Dbf = Pbf + (size_t)Mtot * Qq;                         //  0.52 MB
    u16* G   = Dbf + (size_t)Qq * Qq;                           // 16.78 MB

    k_init<<<dim3(320), dim3(256), 0, stream>>>(
        ew, d_hw, esrc, edst, inv_w, Dbf, bincount, bins, out);
    k_gemm1<<<dim3(1024), dim3(256), 0, stream>>>(P, Dbf, Pbf, G);
    k_gemm2<<<dim3(640), dim3(256), 0, stream>>>(G, Pbf, bincount, bins, inv_w, out);
}